// Round 5
// baseline (407.299 us; speedup 1.0000x reference)
//
#include <hip/hip_runtime.h>
#include <hip/hip_cooperative_groups.h>

namespace cg = cooperative_groups;

// B=8, S=1024, D=1024, H=16, HD=64, R=8, SCALING=2.0, DFF=4096, DC=512, NC=3.
// Single cooperative kernel: 256 blocks x 512 threads, 10 grid.sync()s.
// Attention at query 0 via pullback (no K/V materialization):
//   score[b,h,k] = qh[h,b,:] . h[b,k,:],  qh = q0 pulled through WkE
//   pv[h,b,c] = sum_k softmax(score)[k] h[b,k,c]; ctx = per-head pv . WvE

struct Params {
  const float *x, *Wq, *Aq, *Bq, *Wk, *Ak, *Bk, *Wv, *Av, *Bv, *Wo, *Ao, *Bo;
  const float *ln1g, *ln1b, *ln2g, *ln2b, *W1, *b1, *W2, *b2, *Wc1, *bc1, *Wc2, *bc2;
  unsigned short* hbf;
  float *x0, *q0, *qh, *opart, *ml, *pv, *ctx, *h2, *mid, *pooled, *cmid, *out;
};

__device__ __forceinline__ float blo(unsigned int u) {
  union { unsigned int i; float f; } v; v.i = u << 16; return v.f;
}
__device__ __forceinline__ float bhi(unsigned int u) {
  union { unsigned int i; float f; } v; v.i = u & 0xffff0000u; return v.f;
}
__device__ __forceinline__ unsigned short f2bf(float f) {
  union { float f; unsigned int i; } v; v.f = f;
  unsigned int u = v.i;
  u += 0x7FFFu + ((u >> 16) & 1u);
  return (unsigned short)(u >> 16);
}
__device__ __forceinline__ float gelu_exact(float x) {
  return 0.5f * x * (1.0f + erff(x * 0.70710678118654752440f));
}
__device__ __forceinline__ float wave_sum(float v) {
#pragma unroll
  for (int o = 1; o < 64; o <<= 1) v += __shfl_xor(v, o);
  return v;
}

union SharedU {
  struct { float sX[8][1024]; float sT[8][8][4]; float T[8][8]; float part2[8][8]; } a;
  struct { float q0h[8][64]; float sTk[8][8][4]; float Tk[8][8]; float part[8][8][64]; } b;
  struct { unsigned short hs[16][1024]; float S[32][16]; float smax[16]; float pS[32][16]; } c;
  struct { float am[32]; float al[32]; float e[32]; float Linv; } d;
  struct { float part[32][8]; } e;
};

// T[m][r] = sX[m] . Amat[r]  (rank-8 LoRA inner products), 512-thread block
__device__ __forceinline__ void compute_T(const float (*sX)[1024], const float* Amat,
                                          float (*sT)[8][4], float (*T)[8]) {
  int t = threadIdx.x;
  if (t < 256) {
    int m = t >> 5, r = (t >> 2) & 7, q = t & 3;
    float s = 0.f;
    const float* ar = Amat + r * 1024 + q * 256;
    const float* xr = &sX[m][q * 256];
    for (int j = 0; j < 256; j += 4)
      s += xr[j] * ar[j] + xr[j+1] * ar[j+1] + xr[j+2] * ar[j+2] + xr[j+3] * ar[j+3];
    sT[m][r][q] = s;
  }
  __syncthreads();
  if (t < 64) {
    int m = t >> 3, r = t & 7;
    T[m][r] = sT[m][r][0] + sT[m][r][1] + sT[m][r][2] + sT[m][r][3];
  }
  __syncthreads();
}

// Y[m][col] = sX[m] . W[col] + 2*sum_r Bm[col][r]*T[m][r] (+resid), one wave per col
__device__ __forceinline__ void coldot_lora(const float (*sX)[1024], const float (*T)[8],
                                            const float* W, const float* Bm, int col,
                                            const float* resid, long rstride,
                                            float* Y, int N) {
  int l = threadIdx.x & 63;
  float acc[8] = {0.f, 0.f, 0.f, 0.f, 0.f, 0.f, 0.f, 0.f};
#pragma unroll
  for (int i = 0; i < 4; ++i) {
    int k = i * 256 + l * 4;
    float4 wv = *(const float4*)(W + (size_t)col * 1024 + k);
#pragma unroll
    for (int m = 0; m < 8; ++m) {
      float4 xv = *(const float4*)&sX[m][k];
      acc[m] += wv.x * xv.x + wv.y * xv.y + wv.z * xv.z + wv.w * xv.w;
    }
  }
#pragma unroll
  for (int m = 0; m < 8; ++m) acc[m] = wave_sum(acc[m]);
  if (l == 0) {
#pragma unroll
    for (int m = 0; m < 8; ++m) {
      float v = acc[m];
#pragma unroll
      for (int r = 0; r < 8; ++r) v += 2.f * Bm[col * 8 + r] * T[m][r];
      if (resid) v += resid[(size_t)m * rstride + col];
      Y[(size_t)m * N + col] = v;
    }
  }
}

__global__ __launch_bounds__(512, 2) void mega(Params p) {
  cg::grid_group grid = cg::this_grid();
  const int bid = blockIdx.x;     // 0..255
  const int t = threadIdx.x;      // 0..511
  const int wid = t >> 6, l = t & 63;
  __shared__ SharedU U;

  // ================= p0: LN1 over 8192 rows -> bf16 h; rows 8192..8199 -> x0 fp32
  {
    float4 gv[4], bv4[4];
#pragma unroll
    for (int i = 0; i < 4; ++i) {
      gv[i]  = ((const float4*)p.ln1g)[i * 64 + l];
      bv4[i] = ((const float4*)p.ln1b)[i * 64 + l];
    }
    for (int vr = bid * 8 + wid; vr < 8200; vr += 2048) {
      const float* xr = (vr < 8192) ? (p.x + (size_t)vr * 1024)
                                    : (p.x + (size_t)(vr - 8192) * 1048576);
      float4 xv[4];
#pragma unroll
      for (int i = 0; i < 4; ++i) xv[i] = ((const float4*)xr)[i * 64 + l];
      float s = 0.f, sq = 0.f;
#pragma unroll
      for (int i = 0; i < 4; ++i) {
        s  += xv[i].x + xv[i].y + xv[i].z + xv[i].w;
        sq += xv[i].x * xv[i].x + xv[i].y * xv[i].y + xv[i].z * xv[i].z + xv[i].w * xv[i].w;
      }
      s = wave_sum(s); sq = wave_sum(sq);
      float mu = s * (1.f / 1024.f);
      float rstd = rsqrtf(sq * (1.f / 1024.f) - mu * mu + 1e-5f);
      if (vr < 8192) {
        unsigned short* op = p.hbf + (size_t)vr * 1024;
#pragma unroll
        for (int i = 0; i < 4; ++i) {
          ushort4 o;
          o.x = f2bf((xv[i].x - mu) * rstd * gv[i].x + bv4[i].x);
          o.y = f2bf((xv[i].y - mu) * rstd * gv[i].y + bv4[i].y);
          o.z = f2bf((xv[i].z - mu) * rstd * gv[i].z + bv4[i].z);
          o.w = f2bf((xv[i].w - mu) * rstd * gv[i].w + bv4[i].w);
          *(ushort4*)(op + i * 256 + l * 4) = o;
        }
      } else {
        float* op = p.x0 + (size_t)(vr - 8192) * 1024;
#pragma unroll
        for (int i = 0; i < 4; ++i) {
          float4 o;
          o.x = (xv[i].x - mu) * rstd * gv[i].x + bv4[i].x;
          o.y = (xv[i].y - mu) * rstd * gv[i].y + bv4[i].y;
          o.z = (xv[i].z - mu) * rstd * gv[i].z + bv4[i].z;
          o.w = (xv[i].w - mu) * rstd * gv[i].w + bv4[i].w;
          ((float4*)op)[i * 64 + l] = o;
        }
      }
    }
  }
  grid.sync();

  // ================= p1a: q0 = x0 @ WqE^T (LoRA exact), blocks 0..127, col = bid*8+wid
  if (bid < 128) {
    for (int i = t; i < 2048; i += 512)
      ((float4*)U.a.sX)[i] = ((const float4*)p.x0)[i];
    __syncthreads();
    compute_T(U.a.sX, p.Aq, U.a.sT, U.a.T);
    coldot_lora(U.a.sX, U.a.T, p.Wq, p.Bq, bid * 8 + wid, nullptr, 0, p.q0, 1024);
  }
  grid.sync();

  // ================= p1b: qh[(h*8+b)][c] = sum_d q0[b][h*64+d]*WkE[h*64+d][c]
  {
    int head = bid >> 4, c0 = (bid & 15) * 64;
    { int b = t >> 6, d = t & 63; U.b.q0h[b][d] = p.q0[b * 1024 + head * 64 + d]; }
    __syncthreads();
    if (t < 256) {
      int b = t >> 5, r = (t >> 2) & 7, q = t & 3;
      float s = 0.f;
#pragma unroll
      for (int j = 0; j < 16; ++j) {
        int d = q * 16 + j;
        s += U.b.q0h[b][d] * p.Bk[(head * 64 + d) * 8 + r];
      }
      U.b.sTk[b][r][q] = s;
    }
    __syncthreads();
    if (t < 64) {
      int b = t >> 3, r = t & 7;
      U.b.Tk[b][r] = U.b.sTk[b][r][0] + U.b.sTk[b][r][1] + U.b.sTk[b][r][2] + U.b.sTk[b][r][3];
    }
    __syncthreads();
    int cl = t & 63, seg = t >> 6;   // 8 segs x 8 d
    float acc[8] = {0.f, 0.f, 0.f, 0.f, 0.f, 0.f, 0.f, 0.f};
#pragma unroll
    for (int j = 0; j < 8; ++j) {
      int d = seg * 8 + j;
      float wv = p.Wk[(size_t)(head * 64 + d) * 1024 + c0 + cl];
#pragma unroll
      for (int b = 0; b < 8; ++b) acc[b] += U.b.q0h[b][d] * wv;
    }
#pragma unroll
    for (int b = 0; b < 8; ++b) U.b.part[seg][b][cl] = acc[b];
    __syncthreads();
    { int b = t >> 6, c = t & 63;
      float v = 0.f;
#pragma unroll
      for (int s2 = 0; s2 < 8; ++s2) v += U.b.part[s2][b][c];
      float lv = 0.f;
#pragma unroll
      for (int r = 0; r < 8; ++r) lv += U.b.Tk[b][r] * p.Ak[r * 1024 + c0 + c];
      p.qh[(size_t)(head * 8 + b) * 1024 + c0 + c] = v + 2.f * lv; }
  }
  grid.sync();

  // ================= p2: flash chunk: b=bid&7, kc=bid>>3 (32 k-rows), unnormalized opart + (m,l)
  {
    int b = bid & 7, kc = bid >> 3;
    const unsigned short* hb = p.hbf + (size_t)b * 1048576 + (size_t)kc * 32768;
    float qv[2][16];
#pragma unroll
    for (int hi = 0; hi < 2; ++hi) {
      const float4* qp = (const float4*)(p.qh + (size_t)((wid * 2 + hi) * 8 + b) * 1024 + l * 16);
#pragma unroll
      for (int i = 0; i < 4; ++i) {
        float4 q4 = qp[i];
        qv[hi][i * 4 + 0] = q4.x; qv[hi][i * 4 + 1] = q4.y;
        qv[hi][i * 4 + 2] = q4.z; qv[hi][i * 4 + 3] = q4.w;
      }
    }
    for (int half = 0; half < 2; ++half) {
      for (int i = t; i < 2048; i += 512)
        ((uint4*)U.c.hs)[i] = ((const uint4*)(hb + half * 16384))[i];
      __syncthreads();
      for (int kk = 0; kk < 16; ++kk) {
        const uint4* hp = (const uint4*)&U.c.hs[kk][l * 16];
        uint4 u0 = hp[0], u1 = hp[1];
        float hv[16];
        hv[0]=blo(u0.x); hv[1]=bhi(u0.x); hv[2]=blo(u0.y); hv[3]=bhi(u0.y);
        hv[4]=blo(u0.z); hv[5]=bhi(u0.z); hv[6]=blo(u0.w); hv[7]=bhi(u0.w);
        hv[8]=blo(u1.x); hv[9]=bhi(u1.x); hv[10]=blo(u1.y); hv[11]=bhi(u1.y);
        hv[12]=blo(u1.z); hv[13]=bhi(u1.z); hv[14]=blo(u1.w); hv[15]=bhi(u1.w);
        float s0 = 0.f, s1 = 0.f;
#pragma unroll
        for (int j = 0; j < 16; ++j) { s0 += qv[0][j] * hv[j]; s1 += qv[1][j] * hv[j]; }
        s0 = wave_sum(s0); s1 = wave_sum(s1);
        if (l == 0) {
          U.c.S[half * 16 + kk][wid * 2]     = s0 * 0.125f;
          U.c.S[half * 16 + kk][wid * 2 + 1] = s1 * 0.125f;
        }
      }
      __syncthreads();
    }
    if (t < 16) {
      float m = -1e30f;
      for (int k = 0; k < 32; ++k) m = fmaxf(m, U.c.S[k][t]);
      float ls = 0.f;
      for (int k = 0; k < 32; ++k) ls += expf(U.c.S[k][t] - m);
      U.c.smax[t] = m;
      p.ml[((size_t)(b * 32 + kc) * 16 + t) * 2]     = m;
      p.ml[((size_t)(b * 32 + kc) * 16 + t) * 2 + 1] = ls;
    }
    __syncthreads();
    { int k = t >> 4, h = t & 15;
      U.c.pS[k][h] = expf(U.c.S[k][h] - U.c.smax[h]); }
    __syncthreads();
    int c0 = t * 2;
    float a0[16], a1[16];
#pragma unroll
    for (int h = 0; h < 16; ++h) { a0[h] = 0.f; a1[h] = 0.f; }
    for (int k = 0; k < 32; ++k) {
      unsigned int u = *(const unsigned int*)(hb + (size_t)k * 1024 + c0);
      float h0 = blo(u), h1 = bhi(u);
      float4 p0 = *(const float4*)&U.c.pS[k][0];
      float4 p1 = *(const float4*)&U.c.pS[k][4];
      float4 p2 = *(const float4*)&U.c.pS[k][8];
      float4 p3 = *(const float4*)&U.c.pS[k][12];
      float pk[16] = {p0.x, p0.y, p0.z, p0.w, p1.x, p1.y, p1.z, p1.w,
                      p2.x, p2.y, p2.z, p2.w, p3.x, p3.y, p3.z, p3.w};
#pragma unroll
      for (int h = 0; h < 16; ++h) { a0[h] += pk[h] * h0; a1[h] += pk[h] * h1; }
    }
    float* ob = p.opart + ((size_t)(b * 32 + kc) * 16) * 1024 + c0;
#pragma unroll
    for (int h = 0; h < 16; ++h) {
      float2 o2; o2.x = a0[h]; o2.y = a1[h];
      *(float2*)(ob + (size_t)h * 1024) = o2;
    }
  }
  grid.sync();

  // ================= p3: combine chunks -> pv[(h*8+b)][c]
  if (bid < 128) {
    int hh = bid >> 3, b = bid & 7;
    if (t < 32) {
      U.d.am[t] = p.ml[((size_t)(b * 32 + t) * 16 + hh) * 2];
      U.d.al[t] = p.ml[((size_t)(b * 32 + t) * 16 + hh) * 2 + 1];
    }
    __syncthreads();
    if (t == 0) {
      float M = -1e30f;
      for (int c = 0; c < 32; ++c) M = fmaxf(M, U.d.am[c]);
      float L = 0.f;
      for (int c = 0; c < 32; ++c) {
        float e = expf(U.d.am[c] - M);
        U.d.e[c] = e;
        L += U.d.al[c] * e;
      }
      U.d.Linv = 1.f / L;
    }
    __syncthreads();
    int c0 = t * 2;
    float a0 = 0.f, a1 = 0.f;
#pragma unroll 8
    for (int kc = 0; kc < 32; ++kc) {
      const float2 v = *(const float2*)(p.opart + ((size_t)(b * 32 + kc) * 16 + hh) * 1024 + c0);
      float e = U.d.e[kc];
      a0 += e * v.x; a1 += e * v.y;
    }
    float inv = U.d.Linv;
    float2 o2; o2.x = a0 * inv; o2.y = a1 * inv;
    *(float2*)(p.pv + (size_t)(hh * 8 + b) * 1024 + c0) = o2;
  }
  grid.sync();

  // ================= p4: ctx = per-head pv @ WvE^T (LoRA exact), blocks 0..127
  if (bid < 128) {
    int head = bid >> 3;
    for (int i = t; i < 2048; i += 512)
      ((float4*)U.a.sX)[i] = ((const float4*)(p.pv + (size_t)head * 8192))[i];
    __syncthreads();
    compute_T(U.a.sX, p.Av, U.a.sT, U.a.T);
    coldot_lora(U.a.sX, U.a.T, p.Wv, p.Bv, bid * 8 + wid, nullptr, 0, p.ctx, 1024);
  }
  grid.sync();

  // ================= p5: h2 = ctx @ WoE^T + LoRA + resid x[:,0,:]
  if (bid < 128) {
    for (int i = t; i < 2048; i += 512)
      ((float4*)U.a.sX)[i] = ((const float4*)p.ctx)[i];
    __syncthreads();
    compute_T(U.a.sX, p.Ao, U.a.sT, U.a.T);
    coldot_lora(U.a.sX, U.a.T, p.Wo, p.Bo, bid * 8 + wid, p.x, 1048576, p.h2, 1024);
  }
  grid.sync();

  // ================= p6: LN2 (in-block) + FFN1 -> mid[8][4096]
  {
    for (int i = t; i < 2048; i += 512)
      ((float4*)U.a.sX)[i] = ((const float4*)p.h2)[i];
    __syncthreads();
    {
      int r = wid;  // 8 waves, 8 rows
      float4 xv[4];
#pragma unroll
      for (int i = 0; i < 4; ++i) xv[i] = *(const float4*)&U.a.sX[r][i * 256 + l * 4];
      float s = 0.f, sq = 0.f;
#pragma unroll
      for (int i = 0; i < 4; ++i) {
        s  += xv[i].x + xv[i].y + xv[i].z + xv[i].w;
        sq += xv[i].x * xv[i].x + xv[i].y * xv[i].y + xv[i].z * xv[i].z + xv[i].w * xv[i].w;
      }
      s = wave_sum(s); sq = wave_sum(sq);
      float mu = s * (1.f / 1024.f);
      float rstd = rsqrtf(sq * (1.f / 1024.f) - mu * mu + 1e-5f);
#pragma unroll
      for (int i = 0; i < 4; ++i) {
        float4 g4 = ((const float4*)p.ln2g)[i * 64 + l];
        float4 b4 = ((const float4*)p.ln2b)[i * 64 + l];
        float4 o;
        o.x = (xv[i].x - mu) * rstd * g4.x + b4.x;
        o.y = (xv[i].y - mu) * rstd * g4.y + b4.y;
        o.z = (xv[i].z - mu) * rstd * g4.z + b4.z;
        o.w = (xv[i].w - mu) * rstd * g4.w + b4.w;
        *(float4*)&U.a.sX[r][i * 256 + l * 4] = o;
      }
    }
    __syncthreads();
    float acc[2][8];
#pragma unroll
    for (int cc = 0; cc < 2; ++cc)
#pragma unroll
      for (int m = 0; m < 8; ++m) acc[cc][m] = 0.f;
#pragma unroll
    for (int i = 0; i < 4; ++i) {
      int k = i * 256 + l * 4;
      float4 xv[8];
#pragma unroll
      for (int m = 0; m < 8; ++m) xv[m] = *(const float4*)&U.a.sX[m][k];
#pragma unroll
      for (int cc = 0; cc < 2; ++cc) {
        int col = bid * 16 + wid * 2 + cc;
        float4 wv = *(const float4*)(p.W1 + (size_t)col * 1024 + k);
#pragma unroll
        for (int m = 0; m < 8; ++m)
          acc[cc][m] += wv.x * xv[m].x + wv.y * xv[m].y + wv.z * xv[m].z + wv.w * xv[m].w;
      }
    }
#pragma unroll
    for (int cc = 0; cc < 2; ++cc)
#pragma unroll
      for (int m = 0; m < 8; ++m) acc[cc][m] = wave_sum(acc[cc][m]);
    if (l == 0) {
#pragma unroll
      for (int cc = 0; cc < 2; ++cc) {
        int col = bid * 16 + wid * 2 + cc;
        float bb = p.b1[col];
#pragma unroll
        for (int m = 0; m < 8; ++m)
          p.mid[(size_t)m * 4096 + col] = gelu_exact(acc[cc][m] + bb);
      }
    }
  }
  grid.sync();

  // ================= p7: FFN2 + resid -> pooled[8][1024]; col=bid*4+(wid&3), K split by wid>>2
  {
    int col = bid * 4 + (wid & 3);
    int khalf = wid >> 2;
    float acc[8] = {0.f, 0.f, 0.f, 0.f, 0.f, 0.f, 0.f, 0.f};
    for (int ch = 0; ch < 4; ++ch) {
      __syncthreads();
      for (int i = t; i < 2048; i += 512) {
        int m = i >> 8, pp = i & 255;
        ((float4*)U.a.sX[m])[pp] = ((const float4*)(p.mid + (size_t)m * 4096 + ch * 1024))[pp];
      }
      __syncthreads();
#pragma unroll
      for (int i = 0; i < 2; ++i) {
        int k = khalf * 512 + i * 256 + l * 4;
        float4 wv = *(const float4*)(p.W2 + (size_t)col * 4096 + ch * 1024 + k);
#pragma unroll
        for (int m = 0; m < 8; ++m) {
          float4 xv = *(const float4*)&U.a.sX[m][k];
          acc[m] += wv.x * xv.x + wv.y * xv.y + wv.z * xv.z + wv.w * xv.w;
        }
      }
    }
#pragma unroll
    for (int m = 0; m < 8; ++m) acc[m] = wave_sum(acc[m]);
    if (l == 0) {
#pragma unroll
      for (int m = 0; m < 8; ++m) U.a.part2[wid][m] = acc[m];
    }
    __syncthreads();
    if (t < 32) {
      int cl = t >> 3, b = t & 7;
      int col2 = bid * 4 + cl;
      float v = U.a.part2[cl][b] + U.a.part2[cl + 4][b] + p.b2[col2] +
                p.h2[(size_t)b * 1024 + col2];
      p.pooled[(size_t)b * 1024 + col2] = v;
    }
  }
  grid.sync();

  // ================= p8: cmid = gelu(pooled @ Wc1^T + bc1), blocks 0..63, col=bid*8+wid
  if (bid < 64) {
    for (int i = t; i < 2048; i += 512)
      ((float4*)U.a.sX)[i] = ((const float4*)p.pooled)[i];
    __syncthreads();
    int col = bid * 8 + wid;
    float acc[8] = {0.f, 0.f, 0.f, 0.f, 0.f, 0.f, 0.f, 0.f};
#pragma unroll
    for (int i = 0; i < 4; ++i) {
      int k = i * 256 + l * 4;
      float4 wv = *(const float4*)(p.Wc1 + (size_t)col * 1024 + k);
#pragma unroll
      for (int m = 0; m < 8; ++m) {
        float4 xv = *(const float4*)&U.a.sX[m][k];
        acc[m] += wv.x * xv.x + wv.y * xv.y + wv.z * xv.z + wv.w * xv.w;
      }
    }
#pragma unroll
    for (int m = 0; m < 8; ++m) acc[m] = wave_sum(acc[m]);
    if (l == 0) {
      float bb = p.bc1[col];
#pragma unroll
      for (int m = 0; m < 8; ++m)
        p.cmid[(size_t)m * 512 + col] = gelu_exact(acc[m] + bb);
    }
  }
  grid.sync();

  // ================= p9: logits (block 0)
  if (bid == 0) {
    int o = t >> 3, s = t & 7;
    float a = 0.f;
    if (t < 192 && o < 24) {
      int b = o / 3, n = o % 3;
      const float* xx = p.cmid + b * 512 + s * 64;
      const float* ww = p.Wc2 + n * 512 + s * 64;
#pragma unroll
      for (int k = 0; k < 64; ++k) a += xx[k] * ww[k];
    }
    if (t < 256) U.e.part[o][s] = a;
    __syncthreads();
    if (t < 24) {
      float v = p.bc2[t % 3];
#pragma unroll
      for (int ss = 0; ss < 8; ++ss) v += U.e.part[t][ss];
      p.out[t] = v;
    }
  }
}

extern "C" void kernel_launch(void* const* d_in, const int* in_sizes, int n_in,
                              void* d_out, int out_size, void* d_ws, size_t ws_size,
                              hipStream_t stream) {
  char* ws = (char*)d_ws;
  size_t off = 0;
  auto alloc = [&](size_t bytes) {
    void* pp = ws + off;
    off += (bytes + 255) & ~(size_t)255;
    return pp;
  };

  Params hp;
  hp.x    = (const float*)d_in[0];
  hp.Wq   = (const float*)d_in[1];
  hp.Aq   = (const float*)d_in[2];
  hp.Bq   = (const float*)d_in[3];
  hp.Wk   = (const float*)d_in[4];
  hp.Ak   = (const float*)d_in[5];
  hp.Bk   = (const float*)d_in[6];
  hp.Wv   = (const float*)d_in[7];
  hp.Av   = (const float*)d_in[8];
  hp.Bv   = (const float*)d_in[9];
  hp.Wo   = (const float*)d_in[10];
  hp.Ao   = (const float*)d_in[11];
  hp.Bo   = (const float*)d_in[12];
  hp.ln1g = (const float*)d_in[13];
  hp.ln1b = (const float*)d_in[14];
  hp.ln2g = (const float*)d_in[15];
  hp.ln2b = (const float*)d_in[16];
  hp.W1   = (const float*)d_in[17];
  hp.b1   = (const float*)d_in[18];
  hp.W2   = (const float*)d_in[19];
  hp.b2   = (const float*)d_in[20];
  hp.Wc1  = (const float*)d_in[21];
  hp.bc1  = (const float*)d_in[22];
  hp.Wc2  = (const float*)d_in[23];
  hp.bc2  = (const float*)d_in[24];

  hp.hbf    = (unsigned short*)alloc((size_t)8192 * 1024 * 2);
  hp.x0     = (float*)alloc(8 * 1024 * 4);
  hp.q0     = (float*)alloc(8 * 1024 * 4);
  hp.qh     = (float*)alloc((size_t)128 * 1024 * 4);
  hp.opart  = (float*)alloc((size_t)256 * 16 * 1024 * 4);
  hp.ml     = (float*)alloc((size_t)8 * 32 * 16 * 2 * 4);
  hp.pv     = (float*)alloc((size_t)128 * 1024 * 4);
  hp.ctx    = (float*)alloc(8 * 1024 * 4);
  hp.h2     = (float*)alloc(8 * 1024 * 4);
  hp.mid    = (float*)alloc((size_t)8 * 4096 * 4);
  hp.pooled = (float*)alloc(8 * 1024 * 4);
  hp.cmid   = (float*)alloc(8 * 512 * 4);
  hp.out    = (float*)d_out;

  void* args[] = { &hp };
  hipLaunchCooperativeKernel(reinterpret_cast<void*>(mega), dim3(256), dim3(512),
                             args, 0, stream);
}

// Round 6
// 158.107 us; speedup vs baseline: 2.5761x; 2.5761x over previous
//
#include <hip/hip_runtime.h>
#include <hip/hip_bf16.h>

// B=8, S=1024, D=1024, H=16, HD=64, R=8, SCALING=2.0, DFF=4096, DC=512, NC=3.
// Output depends only on h[:,0]. Attention at query 0 via pullback:
//   score[b,h,k] = qh[h,b,:] . h[b,k,:],  qh = q0 pulled through WkE
//   pv[h,b,c] = sum_k softmax(score)[k] h[b,k,c]; ctx = per-head pv . WvE
// 11 launches; flash-chunked attention (scores+local softmax+PV in one kernel).

__device__ __forceinline__ float blo(unsigned int u) {
  union { unsigned int i; float f; } v; v.i = u << 16; return v.f;
}
__device__ __forceinline__ float bhi(unsigned int u) {
  union { unsigned int i; float f; } v; v.i = u & 0xffff0000u; return v.f;
}
__device__ __forceinline__ unsigned short f2bf(float f) {
  union { float f; unsigned int i; } v; v.f = f;
  unsigned int u = v.i;
  u += 0x7FFFu + ((u >> 16) & 1u);
  return (unsigned short)(u >> 16);
}
__device__ __forceinline__ float gelu_exact(float x) {
  return 0.5f * x * (1.0f + erff(x * 0.70710678118654752440f));
}
__device__ __forceinline__ float wave_sum(float v) {
#pragma unroll
  for (int o = 1; o < 64; o <<= 1) v += __shfl_xor(v, o);
  return v;
}

// ---------------- LN1: blocks 0..8191 -> h bf16; blocks 8192..8199 -> x0 fp32
__global__ __launch_bounds__(256) void ln_fused(
    const float* __restrict__ x, const float* __restrict__ g,
    const float* __restrict__ b, unsigned short* __restrict__ hbf,
    float* __restrict__ x0) {
  int blk = blockIdx.x;
  int f32out = (blk >= 8192);
  const float* xr = f32out ? (x + (size_t)(blk - 8192) * 1048576)
                           : (x + (size_t)blk * 1024);
  int t = threadIdx.x;
  float4 v = ((const float4*)xr)[t];
  float s  = v.x + v.y + v.z + v.w;
  float sq = v.x * v.x + v.y * v.y + v.z * v.z + v.w * v.w;
#pragma unroll
  for (int o = 32; o; o >>= 1) { s += __shfl_down(s, o); sq += __shfl_down(sq, o); }
  __shared__ float rs_[4], rq_[4], stat[2];
  int w = t >> 6, l = t & 63;
  if (l == 0) { rs_[w] = s; rq_[w] = sq; }
  __syncthreads();
  if (t == 0) {
    float S = rs_[0] + rs_[1] + rs_[2] + rs_[3];
    float Q = rq_[0] + rq_[1] + rq_[2] + rq_[3];
    float mu = S * (1.0f / 1024.0f);
    float var = Q * (1.0f / 1024.0f) - mu * mu;
    stat[0] = mu; stat[1] = rsqrtf(var + 1e-5f);
  }
  __syncthreads();
  float mu = stat[0], rstd = stat[1];
  float4 gg = ((const float4*)g)[t];
  float4 bb = ((const float4*)b)[t];
  float o0 = (v.x - mu) * rstd * gg.x + bb.x;
  float o1 = (v.y - mu) * rstd * gg.y + bb.y;
  float o2 = (v.z - mu) * rstd * gg.z + bb.z;
  float o3 = (v.w - mu) * rstd * gg.w + bb.w;
  if (f32out) {
    float* op = x0 + (size_t)(blk - 8192) * 1024 + t * 4;
    op[0] = o0; op[1] = o1; op[2] = o2; op[3] = o3;
  } else {
    unsigned short* op = hbf + (size_t)blk * 1024 + t * 4;
    op[0] = f2bf(o0); op[1] = f2bf(o1); op[2] = f2bf(o2); op[3] = f2bf(o3);
  }
}

// ---------------- skinny GEMM: Y[8][N] = f(X[8][K] @ W[N][K]^T + bias [+LoRA] [+resid])
template <int CPW>
__global__ __launch_bounds__(256) void skinny_gemm(
    const float* __restrict__ X, long xrs, long xhs,
    const float* __restrict__ W, const float* __restrict__ bias,
    const float* __restrict__ Amat, const float* __restrict__ Bmat,
    const float* __restrict__ resid, long rstride,
    float* __restrict__ Y, int N, int K, int do_gelu) {
  __shared__ float sX[8][1024];
  __shared__ float sT[8][8][4];
  __shared__ float T[8][8];
  int t = threadIdx.x, w = t >> 6, l = t & 63;
  int bcol = blockIdx.x * (4 * CPW);
  int col0 = bcol + w * CPW;
  int head = bcol >> 6;
  const float* Xb = X + (size_t)head * xhs;
  float acc[CPW][8];
#pragma unroll
  for (int c = 0; c < CPW; ++c)
#pragma unroll
    for (int m = 0; m < 8; ++m) acc[c][m] = 0.f;
  for (int kc = 0; kc < K; kc += 1024) {
    for (int i = t; i < 2048; i += 256) {
      int m = i >> 8, p = i & 255;
      ((float4*)sX[m])[p] = *(const float4*)(Xb + (size_t)m * xrs + kc + p * 4);
    }
    __syncthreads();
    if (Amat && kc == 0) {
      int m = t >> 5, r = (t >> 2) & 7, q = t & 3;
      float s = 0.f;
      const float* ar = Amat + r * 1024 + q * 256;
      const float* xr = &sX[m][q * 256];
      for (int j = 0; j < 256; j += 4)
        s += xr[j] * ar[j] + xr[j+1] * ar[j+1] + xr[j+2] * ar[j+2] + xr[j+3] * ar[j+3];
      sT[m][r][q] = s;
      __syncthreads();
      if (t < 64) {
        int mm = t >> 3, rr = t & 7;
        T[mm][rr] = sT[mm][rr][0] + sT[mm][rr][1] + sT[mm][rr][2] + sT[mm][rr][3];
      }
      __syncthreads();
    }
#pragma unroll
    for (int i = 0; i < 4; ++i) {
      int k = i * 256 + l * 4;
      float4 xv[8];
#pragma unroll
      for (int m = 0; m < 8; ++m) xv[m] = *(const float4*)&sX[m][k];
#pragma unroll
      for (int c = 0; c < CPW; ++c) {
        float4 wv = *(const float4*)(W + (size_t)(col0 + c) * K + kc + k);
#pragma unroll
        for (int m = 0; m < 8; ++m)
          acc[c][m] += wv.x * xv[m].x + wv.y * xv[m].y + wv.z * xv[m].z + wv.w * xv[m].w;
      }
    }
    __syncthreads();
  }
#pragma unroll
  for (int c = 0; c < CPW; ++c)
#pragma unroll
    for (int m = 0; m < 8; ++m) {
      float v = acc[c][m];
#pragma unroll
      for (int o = 32; o; o >>= 1) v += __shfl_down(v, o);
      acc[c][m] = v;
    }
  if (l == 0) {
#pragma unroll
    for (int c = 0; c < CPW; ++c) {
      int col = col0 + c;
      float bv = bias ? bias[col] : 0.f;
      float lb[8];
      if (Amat) {
#pragma unroll
        for (int r = 0; r < 8; ++r) lb[r] = Bmat[col * 8 + r];
      }
#pragma unroll
      for (int m = 0; m < 8; ++m) {
        float v = acc[c][m] + bv;
        if (Amat) {
#pragma unroll
          for (int r = 0; r < 8; ++r) v += 2.0f * lb[r] * T[m][r];
        }
        if (do_gelu) v = gelu_exact(v);
        if (resid) v += resid[(size_t)m * rstride + col];
        Y[(size_t)m * N + col] = v;
      }
    }
  }
}

// ---------------- pullback: qh[(h*8+b)][c] = sum_{d<64} q0[b][h*64+d]*WkE[h*64+d][c]
__global__ __launch_bounds__(256) void pullback_kernel(
    const float* __restrict__ q0, const float* __restrict__ Wk,
    const float* __restrict__ Ak, const float* __restrict__ Bk,
    float* __restrict__ qh) {
  int head = blockIdx.x >> 2, cchunk = blockIdx.x & 3;
  int t = threadIdx.x;
  int c = cchunk * 256 + t;
  __shared__ float sq[8][64];
  __shared__ float sT[8][8][4];
  __shared__ float T[8][8];
  if (t < 512) { int b = t >> 6, d = t & 63; sq[b][d] = q0[b * 1024 + head * 64 + d]; }
  __syncthreads();
  {
    int b = t >> 5, r = (t >> 2) & 7, q = t & 3;
    float s = 0.f;
#pragma unroll
    for (int j = 0; j < 16; ++j) {
      int d = q * 16 + j;
      s += sq[b][d] * Bk[(head * 64 + d) * 8 + r];
    }
    sT[b][r][q] = s;
  }
  __syncthreads();
  if (t < 64) {
    int b = t >> 3, r = t & 7;
    T[b][r] = sT[b][r][0] + sT[b][r][1] + sT[b][r][2] + sT[b][r][3];
  }
  __syncthreads();
  float acc[8] = {0.f, 0.f, 0.f, 0.f, 0.f, 0.f, 0.f, 0.f};
#pragma unroll 4
  for (int d = 0; d < 64; ++d) {
    float wv = Wk[(size_t)(head * 64 + d) * 1024 + c];
#pragma unroll
    for (int b = 0; b < 8; ++b) acc[b] += sq[b][d] * wv;
  }
  float av[8];
#pragma unroll
  for (int r = 0; r < 8; ++r) av[r] = Ak[r * 1024 + c];
#pragma unroll
  for (int b = 0; b < 8; ++b) {
    float v = acc[b];
#pragma unroll
    for (int r = 0; r < 8; ++r) v += 2.0f * T[b][r] * av[r];
    qh[(size_t)(head * 8 + b) * 1024 + c] = v;
  }
}

// ---------------- attn_flash: block (b, kc): 32 k-rows; QK^T + local softmax + PV partial
// 512 threads = 8 waves; wave w handles heads {w, w+8} (qh in registers).
// h read directly from global (L2-hot, coalesced, no LDS staging -> no conflicts).
__global__ __launch_bounds__(512) void attn_flash(
    const float* __restrict__ qh, const unsigned short* __restrict__ hbf,
    float* __restrict__ opart, float* __restrict__ ml) {
  int b = blockIdx.x & 7, kc = blockIdx.x >> 3;
  int t = threadIdx.x, wid = t >> 6, l = t & 63;
  __shared__ float S[32][16];
  __shared__ float smax[16];
  __shared__ float pS[32][16];
  const unsigned short* hb = hbf + (size_t)b * 1048576 + (size_t)kc * 32768;
  // qh fragments for this wave's 2 heads
  float qv[2][16];
#pragma unroll
  for (int hi = 0; hi < 2; ++hi) {
    const float4* qp = (const float4*)(qh + (size_t)((hi * 8 + wid) * 8 + b) * 1024 + l * 16);
#pragma unroll
    for (int i = 0; i < 4; ++i) {
      float4 q4 = qp[i];
      qv[hi][i * 4 + 0] = q4.x; qv[hi][i * 4 + 1] = q4.y;
      qv[hi][i * 4 + 2] = q4.z; qv[hi][i * 4 + 3] = q4.w;
    }
  }
  for (int k = 0; k < 32; ++k) {
    const uint4* hp = (const uint4*)(hb + (size_t)k * 1024 + l * 16);
    uint4 u0 = hp[0], u1 = hp[1];
    float hv[16];
    hv[0]=blo(u0.x); hv[1]=bhi(u0.x); hv[2]=blo(u0.y); hv[3]=bhi(u0.y);
    hv[4]=blo(u0.z); hv[5]=bhi(u0.z); hv[6]=blo(u0.w); hv[7]=bhi(u0.w);
    hv[8]=blo(u1.x); hv[9]=bhi(u1.x); hv[10]=blo(u1.y); hv[11]=bhi(u1.y);
    hv[12]=blo(u1.z); hv[13]=bhi(u1.z); hv[14]=blo(u1.w); hv[15]=bhi(u1.w);
    float s0 = 0.f, s1 = 0.f;
#pragma unroll
    for (int j = 0; j < 16; ++j) { s0 += qv[0][j] * hv[j]; s1 += qv[1][j] * hv[j]; }
    s0 = wave_sum(s0); s1 = wave_sum(s1);
    if (l == 0) {
      S[k][wid]     = s0 * 0.125f;
      S[k][wid + 8] = s1 * 0.125f;
    }
  }
  __syncthreads();
  if (t < 16) {
    float m = -1e30f;
    for (int k = 0; k < 32; ++k) m = fmaxf(m, S[k][t]);
    float ls = 0.f;
    for (int k = 0; k < 32; ++k) ls += expf(S[k][t] - m);
    smax[t] = m;
    ml[((size_t)(b * 32 + kc) * 16 + t) * 2]     = m;
    ml[((size_t)(b * 32 + kc) * 16 + t) * 2 + 1] = ls;
  }
  __syncthreads();
  { int k = t >> 4, h = t & 15;
    pS[k][h] = expf(S[k][h] - smax[h]); }
  __syncthreads();
  int c0 = t * 2;
  float a0[16], a1[16];
#pragma unroll
  for (int h = 0; h < 16; ++h) { a0[h] = 0.f; a1[h] = 0.f; }
  for (int k = 0; k < 32; ++k) {
    unsigned int u = *(const unsigned int*)(hb + (size_t)k * 1024 + c0);
    float h0 = blo(u), h1 = bhi(u);
    float4 p0 = *(const float4*)&pS[k][0];
    float4 p1 = *(const float4*)&pS[k][4];
    float4 p2 = *(const float4*)&pS[k][8];
    float4 p3 = *(const float4*)&pS[k][12];
    float pk[16] = {p0.x, p0.y, p0.z, p0.w, p1.x, p1.y, p1.z, p1.w,
                    p2.x, p2.y, p2.z, p2.w, p3.x, p3.y, p3.z, p3.w};
#pragma unroll
    for (int h = 0; h < 16; ++h) { a0[h] += pk[h] * h0; a1[h] += pk[h] * h1; }
  }
  float* ob = opart + ((size_t)(b * 32 + kc) * 16) * 1024 + c0;
#pragma unroll
  for (int h = 0; h < 16; ++h) {
    float2 o2; o2.x = a0[h]; o2.y = a1[h];
    *(float2*)(ob + (size_t)h * 1024) = o2;
  }
}

// ---------------- combine: pv[(h*8+b)][c] = sum_kc e_kc * opart[(b*32+kc)*16+h][c] / L
__global__ __launch_bounds__(256) void combine_kernel(
    const float* __restrict__ opart, const float* __restrict__ ml,
    float* __restrict__ pv) {
  int blk = blockIdx.x;            // 128 = h*8 + b
  int hh = blk >> 3, b = blk & 7;
  int t = threadIdx.x;
  __shared__ float am[32], al[32], e[32], Linv;
  if (t < 32) {
    am[t] = ml[((size_t)(b * 32 + t) * 16 + hh) * 2];
    al[t] = ml[((size_t)(b * 32 + t) * 16 + hh) * 2 + 1];
  }
  __syncthreads();
  if (t == 0) {
    float M = -1e30f;
    for (int c = 0; c < 32; ++c) M = fmaxf(M, am[c]);
    float L = 0.f;
    for (int c = 0; c < 32; ++c) {
      float ee = expf(am[c] - M);
      e[c] = ee;
      L += al[c] * ee;
    }
    Linv = 1.f / L;
  }
  __syncthreads();
  int c0 = t * 4;
  float4 a = (float4){0.f, 0.f, 0.f, 0.f};
#pragma unroll 8
  for (int kc = 0; kc < 32; ++kc) {
    float4 v = *(const float4*)(opart + ((size_t)(b * 32 + kc) * 16 + hh) * 1024 + c0);
    float ee = e[kc];
    a.x += ee * v.x; a.y += ee * v.y; a.z += ee * v.z; a.w += ee * v.w;
  }
  float inv = Linv;
  a.x *= inv; a.y *= inv; a.z *= inv; a.w *= inv;
  *(float4*)(pv + (size_t)(hh * 8 + b) * 1024 + c0) = a;
}

// ---------------- LN2 (in-block, redundant) + FFN1: mid[8][4096] = gelu(LN2(h2) @ W1^T + b1)
__global__ __launch_bounds__(256) void ln2_ffn1(
    const float* __restrict__ h2, const float* __restrict__ g,
    const float* __restrict__ bb, const float* __restrict__ W1,
    const float* __restrict__ b1, float* __restrict__ mid) {
  __shared__ float sX[8][1024];
  int t = threadIdx.x, w = t >> 6, l = t & 63;
  for (int i = t; i < 2048; i += 256)
    ((float4*)sX)[i] = ((const float4*)h2)[i];
  __syncthreads();
  // LN2: wave w handles rows w and w+4
#pragma unroll
  for (int rr = 0; rr < 2; ++rr) {
    int r = w + rr * 4;
    float4 xv[4];
#pragma unroll
    for (int i = 0; i < 4; ++i) xv[i] = *(const float4*)&sX[r][i * 256 + l * 4];
    float s = 0.f, sq = 0.f;
#pragma unroll
    for (int i = 0; i < 4; ++i) {
      s  += xv[i].x + xv[i].y + xv[i].z + xv[i].w;
      sq += xv[i].x * xv[i].x + xv[i].y * xv[i].y + xv[i].z * xv[i].z + xv[i].w * xv[i].w;
    }
    s = wave_sum(s); sq = wave_sum(sq);
    float mu = s * (1.f / 1024.f);
    float rstd = rsqrtf(sq * (1.f / 1024.f) - mu * mu + 1e-5f);
#pragma unroll
    for (int i = 0; i < 4; ++i) {
      float4 g4 = ((const float4*)g)[i * 64 + l];
      float4 b4 = ((const float4*)bb)[i * 64 + l];
      float4 o;
      o.x = (xv[i].x - mu) * rstd * g4.x + b4.x;
      o.y = (xv[i].y - mu) * rstd * g4.y + b4.y;
      o.z = (xv[i].z - mu) * rstd * g4.z + b4.z;
      o.w = (xv[i].w - mu) * rstd * g4.w + b4.w;
      *(float4*)&sX[r][i * 256 + l * 4] = o;
    }
  }
  __syncthreads();
  // FFN1: wave w -> 4 cols
  int col0 = blockIdx.x * 16 + w * 4;
  float acc[4][8];
#pragma unroll
  for (int c = 0; c < 4; ++c)
#pragma unroll
    for (int m = 0; m < 8; ++m) acc[c][m] = 0.f;
#pragma unroll
  for (int i = 0; i < 4; ++i) {
    int k = i * 256 + l * 4;
    float4 xv[8];
#pragma unroll
    for (int m = 0; m < 8; ++m) xv[m] = *(const float4*)&sX[m][k];
#pragma unroll
    for (int c = 0; c < 4; ++c) {
      float4 wv = *(const float4*)(W1 + (size_t)(col0 + c) * 1024 + k);
#pragma unroll
      for (int m = 0; m < 8; ++m)
        acc[c][m] += wv.x * xv[m].x + wv.y * xv[m].y + wv.z * xv[m].z + wv.w * xv[m].w;
    }
  }
#pragma unroll
  for (int c = 0; c < 4; ++c)
#pragma unroll
    for (int m = 0; m < 8; ++m) acc[c][m] = wave_sum(acc[c][m]);
  if (l == 0) {
#pragma unroll
    for (int c = 0; c < 4; ++c) {
      int col = col0 + c;
      float bv = b1[col];
#pragma unroll
      for (int m = 0; m < 8; ++m)
        mid[(size_t)m * 4096 + col] = gelu_exact(acc[c][m] + bv);
    }
  }
}

// ---------------- classifier head
__global__ __launch_bounds__(256) void logits_kernel(
    const float* __restrict__ cmid, const float* __restrict__ Wc2,
    const float* __restrict__ bc2, float* __restrict__ out) {
  int t = threadIdx.x;
  int o = t >> 3, s = t & 7;
  float a = 0.f;
  if (o < 24) {
    int b = o / 3, n = o % 3;
    const float* x = cmid + b * 512 + s * 64;
    const float* w = Wc2 + n * 512 + s * 64;
#pragma unroll
    for (int k = 0; k < 64; ++k) a += x[k] * w[k];
  }
  __shared__ float part[32][8];
  part[o][s] = a;
  __syncthreads();
  if (t < 24) {
    float v = bc2[t % 3];
#pragma unroll
    for (int ss = 0; ss < 8; ++ss) v += part[t][ss];
    out[t] = v;
  }
}

extern "C" void kernel_launch(void* const* d_in, const int* in_sizes, int n_in,
                              void* d_out, int out_size, void* d_ws, size_t ws_size,
                              hipStream_t stream) {
  const float* x    = (const float*)d_in[0];
  const float* Wq   = (const float*)d_in[1];
  const float* Aq   = (const float*)d_in[2];
  const float* Bq   = (const float*)d_in[3];
  const float* Wk   = (const float*)d_in[4];
  const float* Ak   = (const float*)d_in[5];
  const float* Bk   = (const float*)d_in[6];
  const float* Wv   = (const float*)d_in[7];
  const float* Av   = (const float*)d_in[8];
  const float* Bv   = (const float*)d_in[9];
  const float* Wo   = (const float*)d_in[10];
  const float* Ao   = (const float*)d_in[11];
  const float* Bo   = (const float*)d_in[12];
  const float* ln1g = (const float*)d_in[13];
  const float* ln1b = (const float*)d_in[14];
  const float* ln2g = (const float*)d_in[15];
  const float* ln2b = (const float*)d_in[16];
  const float* W1   = (const float*)d_in[17];
  const float* b1   = (const float*)d_in[18];
  const float* W2   = (const float*)d_in[19];
  const float* b2   = (const float*)d_in[20];
  const float* Wc1  = (const float*)d_in[21];
  const float* bc1  = (const float*)d_in[22];
  const float* Wc2  = (const float*)d_in[23];
  const float* bc2  = (const float*)d_in[24];

  char* ws = (char*)d_ws;
  size_t off = 0;
  auto alloc = [&](size_t bytes) {
    void* p = ws + off;
    off += (bytes + 255) & ~(size_t)255;
    return p;
  };
  unsigned short* h_bf = (unsigned short*)alloc((size_t)8192 * 1024 * 2);
  float* qh      = (float*)alloc((size_t)128 * 1024 * 4);
  float* opart   = (float*)alloc((size_t)256 * 16 * 1024 * 4);
  float* ml      = (float*)alloc((size_t)8 * 32 * 16 * 2 * 4);
  float* pvb     = (float*)alloc((size_t)128 * 1024 * 4);
  float* x0   = (float*)alloc(8 * 1024 * 4);
  float* q0   = (float*)alloc(8 * 1024 * 4);
  float* ctx0 = (float*)alloc(8 * 1024 * 4);
  float* h2   = (float*)alloc(8 * 1024 * 4);
  float* mid  = (float*)alloc(8 * 4096 * 4);
  float* pooled = (float*)alloc(8 * 1024 * 4);
  float* cmid = (float*)alloc(8 * 512 * 4);

  // 1. LN1: 8192 rows -> bf16 h; +8 blocks -> fp32 x0 (s=0 rows)
  ln_fused<<<8200, 256, 0, stream>>>(x, ln1g, ln1b, h_bf, x0);
  // 2. Q projection (LoRA exact)
  skinny_gemm<1><<<256, 256, 0, stream>>>(x0, 1024, 0, Wq, nullptr, Aq, Bq,
                                          nullptr, 0, q0, 1024, 1024, 0);
  // 3. pullback q0 through WkE -> qh
  pullback_kernel<<<64, 256, 0, stream>>>(q0, Wk, Ak, Bk, qh);
  // 4. flash attention chunks: scores + local softmax + PV partial
  attn_flash<<<256, 512, 0, stream>>>(qh, h_bf, opart, ml);
  // 5. combine with flash rescale
  combine_kernel<<<128, 256, 0, stream>>>(opart, ml, pvb);
  // 6. V projection (per-head pv input, LoRA exact)
  skinny_gemm<1><<<256, 256, 0, stream>>>(pvb, 1024, 8192, Wv, nullptr, Av, Bv,
                                          nullptr, 0, ctx0, 1024, 1024, 0);
  // 7. O projection + LoRA + residual x[:,0,:]
  skinny_gemm<1><<<256, 256, 0, stream>>>(ctx0, 1024, 0, Wo, nullptr, Ao, Bo,
                                          x, 1048576, h2, 1024, 1024, 0);
  // 8. LN2 + FFN1 fused
  ln2_ffn1<<<256, 256, 0, stream>>>(h2, ln2g, ln2b, W1, b1, mid);
  // 9. FFN2 + residual h2
  skinny_gemm<1><<<256, 256, 0, stream>>>(mid, 4096, 0, W2, b2, nullptr, nullptr,
                                          h2, 1024, pooled, 1024, 4096, 0);
  // 10. classifier layer 1
  skinny_gemm<1><<<128, 256, 0, stream>>>(pooled, 1024, 0, Wc1, bc1, nullptr,
                                          nullptr, nullptr, 0, cmid, 512, 1024, 1);
  // 11. logits
  logits_kernel<<<1, 256, 0, stream>>>(cmid, Wc2, bc2, (float*)d_out);
}